// Round 4
// baseline (74.360 us; speedup 1.0000x reference)
//
#include <hip/hip_runtime.h>
#include <hip/hip_bf16.h>
#include <math.h>

// QuantumBottle, fully fused single kernel, packed-FP32 main loop.
// out_j = b_j + sum_{m in {1,cos,sin}^4} G_j[m] * prod_w u_w[m_w],
// u_w = (1, cos(theta_w), sin(theta_w)), theta_w = tanh(z_w)*scale.
// Each block redundantly builds the 81x4 coefficient table C in LDS,
// then evaluates the multilinear form for QB_S samples per thread,
// with samples packed in pairs (ext_vector float2 -> v_pk_fma_f32).

#define QB_S 4   // samples per thread (2 packed pairs)

typedef float v2f __attribute__((ext_vector_type(2)));

__global__ void __launch_bounds__(256) qb_fused(
    const float* __restrict__ z, const float* __restrict__ scale,
    const float* __restrict__ qw, const float* __restrict__ W,
    const float* __restrict__ bias, float* __restrict__ out, int Bn)
{
    __shared__ float sTrig[8][6];
    __shared__ float Vr[16][16], Vi[16][16];
    __shared__ __align__(16) float4 sM[256];
    __shared__ __align__(16) float sC[81 * 4];

    const int tid = threadIdx.x;

    // ---- phase A1: trig table (24 threads, 1 sincos each) ----
    if (tid < 24) {
        const int g = tid / 3, which = tid % 3;
        const float phi = qw[g * 3 + 0], th = qw[g * 3 + 1], om = qw[g * 3 + 2];
        const float ang = (which == 0) ? 0.5f * th
                        : (which == 1) ? 0.5f * (phi + om)
                                       : 0.5f * (phi - om);
        sTrig[g][2 * which + 0] = cosf(ang);
        sTrig[g][2 * which + 1] = sinf(ang);
    }
    __syncthreads();

    // ---- phase A2: simulate circuit columns (16 threads) ----
    if (tid < 16) {
        float ar[16], ai[16];
        #pragma unroll
        for (int i = 0; i < 16; ++i) { ar[i] = (i == tid) ? 1.0f : 0.0f; ai[i] = 0.0f; }

        for (int l = 0; l < 2; ++l) {
            for (int w = 0; w < 4; ++w) {
                const int g = l * 4 + w;
                const float ct  = sTrig[g][0], st  = sTrig[g][1];
                const float epr = sTrig[g][2], epi = -sTrig[g][3];
                const float emr = sTrig[g][4], emi = -sTrig[g][5];
                const float u00r =  epr * ct, u00i =  epi * ct;
                const float u01r = -emr * st, u01i =  emi * st;
                const float u10r =  emr * st, u10i =  emi * st;
                const float u11r =  epr * ct, u11i = -epi * ct;
                const int bit = 1 << (3 - w);
                #pragma unroll
                for (int i = 0; i < 16; ++i) {
                    if (i & bit) continue;
                    const int i1 = i | bit;
                    const float x0r = ar[i],  x0i = ai[i];
                    const float x1r = ar[i1], x1i = ai[i1];
                    ar[i]  = u00r * x0r - u00i * x0i + u01r * x1r - u01i * x1i;
                    ai[i]  = u00r * x0i + u00i * x0r + u01r * x1i + u01i * x1r;
                    ar[i1] = u10r * x0r - u10i * x0i + u11r * x1r - u11i * x1i;
                    ai[i1] = u10r * x0i + u10i * x0r + u11r * x1i + u11i * x1r;
                }
            }
            #pragma unroll
            for (int w = 0; w < 4; ++w) {
                const int cb = 1 << (3 - w);
                const int tb = 1 << (3 - ((w + 1) & 3));
                #pragma unroll
                for (int i = 0; i < 16; ++i) {
                    if ((i & cb) && !(i & tb)) {
                        const int i1 = i | tb;
                        float tr = ar[i]; ar[i] = ar[i1]; ar[i1] = tr;
                        float ti = ai[i]; ai[i] = ai[i1]; ai[i1] = ti;
                    }
                }
            }
        }
        #pragma unroll
        for (int i = 0; i < 16; ++i) { Vr[i][tid] = ar[i]; Vi[i][tid] = ai[i]; }
    }
    __syncthreads();

    // ---- phase B: M_w[k,kp] (256 threads) ----
    {
        const int k = tid >> 4, kp = tid & 15;
        float m0 = 0.f, m1 = 0.f, m2 = 0.f, m3 = 0.f;
        #pragma unroll
        for (int i = 0; i < 16; ++i) {
            const float pr = Vr[i][k] * Vr[i][kp] + Vi[i][k] * Vi[i][kp];
            m0 += ((i >> 3) & 1) ? -pr : pr;
            m1 += ((i >> 2) & 1) ? -pr : pr;
            m2 += ((i >> 1) & 1) ? -pr : pr;
            m3 += ( i       & 1) ? -pr : pr;
        }
        sM[tid] = make_float4(m0, m1, m2, m3);
    }
    __syncthreads();

    // ---- phase C: G_j[m] over the 3^4 basis (81 threads) ----
    if (tid < 81) {
        const int mm[4] = { tid / 27, (tid / 9) % 3, (tid / 3) % 3, tid % 3 };
        float h0 = 0.f, h1 = 0.f, h2 = 0.f, h3 = 0.f;
        #pragma unroll
        for (int t16 = 0; t16 < 16; ++t16) {
            int k = 0, kp = 0;
            float sgn = 0.0625f;
            #pragma unroll
            for (int w = 0; w < 4; ++w) {
                const int b = (t16 >> (3 - w)) & 1;
                int kw, kpw;
                if (mm[w] == 2) { kw = b; kpw = 1 - b; }
                else            { kw = b; kpw = b; if (mm[w] == 1 && b) sgn = -sgn; }
                k  |= kw  << (3 - w);
                kp |= kpw << (3 - w);
            }
            const float4 mv = sM[k * 16 + kp];
            h0 += sgn * mv.x; h1 += sgn * mv.y; h2 += sgn * mv.z; h3 += sgn * mv.w;
        }
        #pragma unroll
        for (int j = 0; j < 4; ++j) {
            sC[tid * 4 + j] = W[j * 4 + 0] * h0 + W[j * 4 + 1] * h1 +
                              W[j * 4 + 2] * h2 + W[j * 4 + 3] * h3;
        }
    }
    __syncthreads();

    // ---- phase D: multilinear form, QB_S samples/thread, packed pairs ----
    const int g      = blockIdx.x * 256 + tid;
    const int stride = gridDim.x * 256;
    const float sc = scale[0];
    const float b0 = bias[0], b1 = bias[1], b2 = bias[2], b3 = bias[3];

    v2f e01v[2][9], e23v[2][9];
    bool valid[QB_S];
    #pragma unroll
    for (int p = 0; p < 2; ++p) {
        #pragma unroll
        for (int l = 0; l < 2; ++l) {
            const int s = 2 * p + l;
            const int idx = g + s * stride;
            valid[s] = (idx < Bn);
            const float4 zv = valid[s] ? reinterpret_cast<const float4*>(z)[idx]
                                       : make_float4(0.f, 0.f, 0.f, 0.f);
            const float zz[4] = { zv.x, zv.y, zv.z, zv.w };
            float c[4], sn[4];
            #pragma unroll
            for (int w = 0; w < 4; ++w) {
                const float x = zz[w];
                const float e = __expf(-2.0f * fabsf(x));
                float t = __fdividef(1.0f - e, 1.0f + e);
                t = copysignf(t, x);
                __sincosf(t * sc, &sn[w], &c[w]);
            }
            const float a01[9] = { 1.0f,  c[1],        sn[1],
                                   c[0],  c[0]*c[1],   c[0]*sn[1],
                                   sn[0], sn[0]*c[1],  sn[0]*sn[1] };
            const float a23[9] = { 1.0f,  c[3],        sn[3],
                                   c[2],  c[2]*c[3],   c[2]*sn[3],
                                   sn[2], sn[2]*c[3],  sn[2]*sn[3] };
            #pragma unroll
            for (int u = 0; u < 9; ++u) {
                if (l == 0) { e01v[p][u].x = a01[u]; e23v[p][u].x = a23[u]; }
                else        { e01v[p][u].y = a01[u]; e23v[p][u].y = a23[u]; }
            }
        }
    }

    v2f acc0[4], acc1[4];
    #pragma unroll
    for (int j = 0; j < 4; ++j) {
        const float bj = (j == 0) ? b0 : (j == 1) ? b1 : (j == 2) ? b2 : b3;
        acc0[j] = (v2f){bj, bj};
        acc1[j] = (v2f){bj, bj};
    }

    #pragma unroll
    for (int u = 0; u < 9; ++u) {
        v2f tj0[4], tj1[4];
        #pragma unroll
        for (int j = 0; j < 4; ++j) { tj0[j] = (v2f)0.0f; tj1[j] = (v2f)0.0f; }
        #pragma unroll
        for (int v = 0; v < 9; ++v) {
            const float4 cc = reinterpret_cast<const float4*>(sC)[u * 9 + v];
            const v2f ev0 = e23v[0][v];
            const v2f ev1 = e23v[1][v];
            tj0[0] = cc.x * ev0 + tj0[0];
            tj0[1] = cc.y * ev0 + tj0[1];
            tj0[2] = cc.z * ev0 + tj0[2];
            tj0[3] = cc.w * ev0 + tj0[3];
            tj1[0] = cc.x * ev1 + tj1[0];
            tj1[1] = cc.y * ev1 + tj1[1];
            tj1[2] = cc.z * ev1 + tj1[2];
            tj1[3] = cc.w * ev1 + tj1[3];
        }
        const v2f eu0 = e01v[0][u];
        const v2f eu1 = e01v[1][u];
        #pragma unroll
        for (int j = 0; j < 4; ++j) {
            acc0[j] = eu0 * tj0[j] + acc0[j];
            acc1[j] = eu1 * tj1[j] + acc1[j];
        }
    }

    #pragma unroll
    for (int p = 0; p < 2; ++p) {
        const v2f* accp = (p == 0) ? acc0 : acc1;
        #pragma unroll
        for (int l = 0; l < 2; ++l) {
            const int s = 2 * p + l;
            const int idx = g + s * stride;
            if (valid[s]) {
                float4 o;
                if (l == 0) o = make_float4(accp[0].x, accp[1].x, accp[2].x, accp[3].x);
                else        o = make_float4(accp[0].y, accp[1].y, accp[2].y, accp[3].y);
                reinterpret_cast<float4*>(out)[idx] = o;
            }
        }
    }
}

extern "C" void kernel_launch(void* const* d_in, const int* in_sizes, int n_in,
                              void* d_out, int out_size, void* d_ws, size_t ws_size,
                              hipStream_t stream) {
    const float* z  = (const float*)d_in[0];   // (B,4)
    const float* sc = (const float*)d_in[1];   // scalar
    const float* qw = (const float*)d_in[2];   // (2,4,3)
    const float* W  = (const float*)d_in[3];   // (4,4)
    const float* bb = (const float*)d_in[4];   // (4,)
    float* out = (float*)d_out;

    const int Bn = in_sizes[0] / 4;
    const int threads_total = (Bn + QB_S - 1) / QB_S;
    const int blocks = (threads_total + 255) / 256;

    hipLaunchKernelGGL(qb_fused, dim3(blocks), dim3(256), 0, stream,
                       z, sc, qw, W, bb, out, Bn);
}